// Round 1
// baseline (550.617 us; speedup 1.0000x reference)
//
#include <hip/hip_runtime.h>
#include <math.h>

#define NFEAT 65536
#define KS1   32        // k slices (2048 each)
#define NTILE 32        // max 64-row group-uniform tiles

// ---- ws layout (float offsets) ----
#define WS_Z     0          // [1024][64] atomic accum mu|ls   (memset)
#define WS_T     65536      // [1024][32] atomic accum T       (memset)
#define WS_SS    98304      // [1024] sum(flat^2)              (memset)
#define WS_SCAL  99328      // [2] freq_loss, roi_loss         (memset; pad to 99392)
#define WS_FSP   99392      // [16][32][64] softplus freq
#define WS_R1SP  132160     // [16][32][32]
#define WS_R2SP  148544     // [16][32][32]
#define WS_G     164928     // [16][32][32] Gram
#define WS_LOSSB 181312     // [1024]
#define WS_SORTI 182336     // int region: order[2048], tg[32], tb[32], tc[32]
#define WS_FT    184832     // [16][64][32] softplus freq, transposed (f major)
#define WS_R1T   217600     // [16][32][32] softplus r1, transposed (r major)
#define WS_WP    233984     // bf16[8192 kg][64 col][8] fragment-packed W1|W2 (8 MB)

typedef __bf16 bf16x8 __attribute__((ext_vector_type(8)));
typedef __bf16 bf16x4 __attribute__((ext_vector_type(4)));
typedef float  floatx4 __attribute__((ext_vector_type(4)));

__device__ __forceinline__ float softplusf(float x) {
    return fmaxf(x, 0.f) + log1pf(expf(-fabsf(x)));
}

__device__ __forceinline__ void glds16(const void* g, void* l) {
    __builtin_amdgcn_global_load_lds(
        (const __attribute__((address_space(1))) unsigned int*)g,
        (__attribute__((address_space(3))) unsigned int*)l, 16, 0, 0);
}

// ---- K0a combined: softplus factors (+transposed copies) | W prepack | sort ----
__global__ __launch_bounds__(256) void k0a(const float* __restrict__ ff,
                                           const float* __restrict__ r1,
                                           const float* __restrict__ r2,
                                           const float* __restrict__ W1,
                                           const float* __restrict__ W2,
                                           const int* __restrict__ groups,
                                           float* __restrict__ ws) {
    const int bid = blockIdx.x, t = threadIdx.x;
    __shared__ int cnt[16], pos[16];
    if (bid < 256) {
        int i = bid * 256 + t;
        if (i < 32768) {
            float sp = softplusf(ff[i]);
            ws[WS_FSP + i] = sp;
            int g = i >> 11, z = (i >> 6) & 31, f = i & 63;
            ws[WS_FT + g * 2048 + f * 32 + z] = sp;
        } else if (i < 49152) {
            int ii = i - 32768;
            float sp = softplusf(r1[ii]);
            ws[WS_R1SP + ii] = sp;
            int g = ii >> 10, z = (ii >> 5) & 31, r = ii & 31;
            ws[WS_R1T + g * 1024 + r * 32 + z] = sp;
        } else {
            int ii = i - 49152;
            ws[WS_R2SP + ii] = softplusf(r2[ii]);
        }
    } else if (bid < 2304) {
        // W prepack: fragment (kg, col) = bf16 W[(kg*8+j)][col], col 0..31->W1, 32..63->W2
        int e = (bid - 256) * 256 + t;          // 0 .. 524287
        int kg = e >> 6, col = e & 63;
        const float* Wsrc = (col < 32 ? W1 : W2) + (size_t)kg * 256 + (col & 31);
        bf16x8 o;
        #pragma unroll
        for (int j = 0; j < 8; j++) o[j] = (__bf16)Wsrc[j * 32];
        *(bf16x8*)((__bf16*)(ws + WS_WP) + (size_t)e * 8) = o;
    } else {
        // ---- sort batches by group into 64-row tiles ----
        int* order = (int*)(ws + WS_SORTI);
        int* tg = order + 2048; int* tb = order + 2080; int* tc = order + 2112;
        if (t < 16) cnt[t] = 0;
        __syncthreads();
        for (int i = t; i < 1024; i += 256) atomicAdd(&cnt[groups[i]], 1);
        __syncthreads();
        if (t == 0) {
            int tt = 0, base = 0;
            for (int g = 0; g < 16; g++) {
                pos[g] = base;
                int c = cnt[g];
                int nt = (c + 63) >> 6;
                for (int j = 0; j < nt; j++) {
                    tg[tt] = g; tb[tt] = base + j * 64;
                    int rem = c - j * 64;
                    tc[tt] = rem < 64 ? rem : 64;
                    tt++;
                }
                base += c;
            }
            for (; tt < NTILE; tt++) { tg[tt] = 0; tb[tt] = 0; tc[tt] = 0; }
        }
        __syncthreads();
        for (int i = t; i < 1024; i += 256) {
            int s = atomicAdd(&pos[groups[i]], 1);
            order[s] = i;
        }
        for (int i = 1024 + t; i < 2048; i += 256) order[i] = 0;
    }
}

// ---- K0b combined: variance losses | per-group Gram ----
__global__ __launch_bounds__(256) void k0b(float* __restrict__ ws) {
    __shared__ float red[256];
    __shared__ float Fg[2048], R1g[1024], R2g[1024];
    const int bid = blockIdx.x, t = threadIdx.x;
    if (bid < 12) {
        int gid = bid * 256 + t;
        float contrib = 0.f;
        if (gid < 2048) {
            const float* F = ws + WS_FSP + gid;
            float sx = 0.f, sx2 = 0.f;
            #pragma unroll
            for (int g = 0; g < 16; g++) { float x = F[g * 2048]; sx += x; sx2 += x * x; }
            contrib = (sx2 - sx * sx * (1.f / 16.f)) * (1.f / 15.f) * (1.f / 64.f);
        } else {
            int p = gid - 2048;
            const float* A = ws + WS_R1SP + p;
            const float* B = ws + WS_R2SP + p;
            float sx = 0.f, sx2 = 0.f, tx = 0.f, tx2 = 0.f;
            #pragma unroll
            for (int g = 0; g < 16; g++) {
                float x = A[g * 1024]; sx += x; sx2 += x * x;
                float y = B[g * 1024]; tx += y; tx2 += y * y;
            }
            contrib = ((sx2 - sx * sx * (1.f / 16.f)) + (tx2 - tx * tx * (1.f / 16.f)))
                      * (1.f / 15.f) * (1.f / 32.f);
        }
        red[t] = contrib;
        __syncthreads();
        for (int o = 128; o > 0; o >>= 1) {
            if (t < o) red[t] += red[t + o];
            __syncthreads();
        }
        if (t == 0) atomicAdd(ws + WS_SCAL + (bid < 8 ? 0 : 1), red[0]);
    } else {
        int g = bid - 12;
        for (int i = t; i < 2048; i += 256) Fg[i] = ws[WS_FSP + g * 2048 + i];
        for (int i = t; i < 1024; i += 256) {
            R1g[i] = ws[WS_R1SP + g * 1024 + i];
            R2g[i] = ws[WS_R2SP + g * 1024 + i];
        }
        __syncthreads();
        for (int p = t; p < 1024; p += 256) {
            int z1 = p >> 5, z2 = p & 31;
            float dF = 0.f;
            for (int f = 0; f < 64; f++) dF += Fg[z1 * 64 + f] * Fg[z2 * 64 + f];
            float d1 = 0.f, d2 = 0.f;
            for (int r = 0; r < 32; r++) {
                d1 += R1g[z1 * 32 + r] * R1g[z2 * 32 + r];
                d2 += R2g[z1 * 32 + r] * R2g[z2 * 32 + r];
            }
            ws[WS_G + g * 1024 + p] = dF * d1 * d2;
        }
    }
}

// ---- fused: GEMM [64 x 2048] x [2048 x 96] per block; N = W1(32)|W2(32)|Kg(32)
//      K-chunk = 64. A: coalesced fp32 load -> swizzled bf16 LDS tile.
//      W: prepacked bf16 fragments, staged via async global_load_lds.
__global__ __launch_bounds__(256) void k_fused(const float* __restrict__ feat,
                                               float* __restrict__ wsf) {
    const int rt = blockIdx.x, ks = blockIdx.y;
    const int* order = (const int*)(wsf + WS_SORTI);
    const int tcnt = order[2112 + rt];
    if (tcnt == 0) return;
    const int g     = order[2048 + rt];
    const int tbase = order[2080 + rt];

    __shared__ __bf16 Asm[2][4096];   // [64 rows][64 k] bf16, XOR-swizzled
    __shared__ __bf16 Bsm[2][6400];   // [8 kg][100 cols][8] bf16

    const int tid = threadIdx.x;
    const int w = tid >> 6, l = tid & 63;
    const int fn = l & 15, q4 = l >> 4;

    // ---- A-load roles: slot i covers row w*16+i*4+q4, k floats [fn*4, fn*4+4) per chunk
    const float* fpA[4];
    int bAi[4], vA[4];
    #pragma unroll
    for (int i = 0; i < 4; i++) {
        int rit = w * 16 + i * 4 + q4;
        vA[i] = (rit < tcnt);
        bAi[i] = order[tbase + rit];
        fpA[i] = feat + (size_t)bAi[i] * NFEAT + (size_t)ks * 2048 + fn * 4;
    }

    // ---- Kg roles
    const int kz = tid & 31, kgT = tid >> 5, hK = kgT >> 2;
    float r2v[8];
    {
        const float* R2p = wsf + WS_R2SP + g * 1024 + kz * 32 + (kgT & 3) * 8;
        float4 a0 = *(const float4*)R2p, a1 = *(const float4*)(R2p + 4);
        r2v[0]=a0.x; r2v[1]=a0.y; r2v[2]=a0.z; r2v[3]=a0.w;
        r2v[4]=a1.x; r2v[5]=a1.y; r2v[6]=a1.z; r2v[7]=a1.w;
    }
    const float* Ftp  = wsf + WS_FT  + g * 2048 + (ks * 2) * 32 + kz;  // +[(cc>>4)*32]
    const float* R1tp = wsf + WS_R1T + g * 1024 + kz;                  // +[r*32]

    const __bf16* wp = (const __bf16*)(wsf + WS_WP);
    const size_t kgbase = (size_t)ks * 256;    // + cc*8 + kg

    const float4 f4z = make_float4(0.f, 0.f, 0.f, 0.f);
    float4 vA4[4];
    float ssl[4] = {0.f, 0.f, 0.f, 0.f};

#define ISSUE(buf, cc) do { \
    glds16(wp + ((kgbase + (size_t)(cc) * 8 + (size_t)w) * 64 + (size_t)l) * 8, \
           &Bsm[buf][w * 800]); \
    glds16(wp + ((kgbase + (size_t)(cc) * 8 + 4 + (size_t)w) * 64 + (size_t)l) * 8, \
           &Bsm[buf][(4 + w) * 800]); \
    vA4[0] = vA[0] ? *(const float4*)(fpA[0] + (cc) * 64) : f4z; \
    vA4[1] = vA[1] ? *(const float4*)(fpA[1] + (cc) * 64) : f4z; \
    vA4[2] = vA[2] ? *(const float4*)(fpA[2] + (cc) * 64) : f4z; \
    vA4[3] = vA[3] ? *(const float4*)(fpA[3] + (cc) * 64) : f4z; \
} while (0)

#define ASTORE(buf, i) do { \
    float4 v = vA4[i]; \
    ssl[i] += v.x * v.x + v.y * v.y + v.z * v.z + v.w * v.w; \
    const int row_ = w * 16 + (i) * 4 + q4; \
    const int byt_ = (row_ * 128 + fn * 8) ^ ((row_ & 7) << 4); \
    bf16x4 a_; a_[0] = (__bf16)v.x; a_[1] = (__bf16)v.y; \
    a_[2] = (__bf16)v.z; a_[3] = (__bf16)v.w; \
    *(bf16x4*)((char*)&Asm[buf][0] + byt_) = a_; \
} while (0)

#define WSTAGE(buf, cc) do { \
    float cf_ = Ftp[((cc) >> 4) * 32] * R1tp[((((cc) * 2) + hK) & 31) * 32]; \
    bf16x8 pk_; \
    pk_[0]=(__bf16)(cf_*r2v[0]); pk_[1]=(__bf16)(cf_*r2v[1]); \
    pk_[2]=(__bf16)(cf_*r2v[2]); pk_[3]=(__bf16)(cf_*r2v[3]); \
    pk_[4]=(__bf16)(cf_*r2v[4]); pk_[5]=(__bf16)(cf_*r2v[5]); \
    pk_[6]=(__bf16)(cf_*r2v[6]); pk_[7]=(__bf16)(cf_*r2v[7]); \
    *(bf16x8*)&Bsm[buf][(kgT * 100 + 64 + kz) * 8] = pk_; \
    ASTORE(buf, 0); ASTORE(buf, 1); ASTORE(buf, 2); ASTORE(buf, 3); \
} while (0)

    // ---- prologue: stage chunk 0 ----
    ISSUE(0, 0);
    WSTAGE(0, 0);
    __syncthreads();

    floatx4 acc0 = {0,0,0,0}, acc1 = {0,0,0,0}, acc2 = {0,0,0,0};
    floatx4 acc3 = {0,0,0,0}, acc4 = {0,0,0,0}, acc5 = {0,0,0,0};

    const int arow = w * 16 + fn;
    #pragma unroll 2
    for (int cc = 0; cc < 32; cc++) {
        const int cur = cc & 1, nxt = cur ^ 1;
        if (cc < 31) ISSUE(nxt, cc + 1);
        // compute chunk cc
        #pragma unroll
        for (int kq = 0; kq < 2; kq++) {
            int rbyt = (arow * 128 + (kq * 4 + q4) * 16) ^ ((arow & 7) << 4);
            bf16x8 af = *(const bf16x8*)((const char*)&Asm[cur][0] + rbyt);
            const __bf16* bb = &Bsm[cur][((kq * 4 + q4) * 100 + fn) * 8];
            bf16x8 b0 = *(const bf16x8*)(bb);
            bf16x8 b1 = *(const bf16x8*)(bb + 128);
            bf16x8 b2 = *(const bf16x8*)(bb + 256);
            bf16x8 b3 = *(const bf16x8*)(bb + 384);
            bf16x8 b4 = *(const bf16x8*)(bb + 512);
            bf16x8 b5 = *(const bf16x8*)(bb + 640);
            acc0 = __builtin_amdgcn_mfma_f32_16x16x32_bf16(af, b0, acc0, 0, 0, 0);
            acc1 = __builtin_amdgcn_mfma_f32_16x16x32_bf16(af, b1, acc1, 0, 0, 0);
            acc2 = __builtin_amdgcn_mfma_f32_16x16x32_bf16(af, b2, acc2, 0, 0, 0);
            acc3 = __builtin_amdgcn_mfma_f32_16x16x32_bf16(af, b3, acc3, 0, 0, 0);
            acc4 = __builtin_amdgcn_mfma_f32_16x16x32_bf16(af, b4, acc4, 0, 0, 0);
            acc5 = __builtin_amdgcn_mfma_f32_16x16x32_bf16(af, b5, acc5, 0, 0, 0);
        }
        if (cc < 31) WSTAGE(nxt, cc + 1);
        __syncthreads();
    }
#undef ISSUE
#undef ASTORE
#undef WSTAGE

    // ---- epilogue ----
    #pragma unroll
    for (int i = 0; i < 4; i++) {
        float s = ssl[i];
        s += __shfl_xor(s, 1, 64);
        s += __shfl_xor(s, 2, 64);
        s += __shfl_xor(s, 4, 64);
        s += __shfl_xor(s, 8, 64);
        if (fn == 0 && vA[i]) atomicAdd(wsf + WS_SS + bAi[i], s);
    }
    #pragma unroll
    for (int r = 0; r < 4; r++) {
        int rit = w * 16 + q4 * 4 + r;
        if (rit < tcnt) {
            int b = order[tbase + rit];
            atomicAdd(wsf + WS_Z + b * 64 +  0 + fn, acc0[r]);
            atomicAdd(wsf + WS_Z + b * 64 + 16 + fn, acc1[r]);
            atomicAdd(wsf + WS_Z + b * 64 + 32 + fn, acc2[r]);
            atomicAdd(wsf + WS_Z + b * 64 + 48 + fn, acc3[r]);
            atomicAdd(wsf + WS_T + b * 32 +  0 + fn, acc4[r]);
            atomicAdd(wsf + WS_T + b * 32 + 16 + fn, acc5[r]);
        }
    }
}

// ---- K3: per-batch epilogue ----
__global__ __launch_bounds__(64) void k3_batch(const float* __restrict__ W1,
                                               const float* __restrict__ W2,
                                               const float* __restrict__ b1,
                                               const float* __restrict__ b2,
                                               const float* __restrict__ gemb,
                                               const float* __restrict__ noise,
                                               const float* __restrict__ linW,
                                               const float* __restrict__ linb,
                                               const float* __restrict__ lbias,
                                               const int* __restrict__ groups,
                                               const int* __restrict__ labels,
                                               const float* __restrict__ weights,
                                               float* __restrict__ ws) {
    const int b = blockIdx.x;
    const int t = threadIdx.x;
    const int g = groups[b];
    float sum = ws[WS_Z + b * 64 + t];

    __shared__ float s_mu[32], s_sig[32], s_zs0[32], s_zs[32], s_P[32], s_red[96];
    float ge0 = gemb[g * 2], ge1 = gemb[g * 2 + 1];
    if (t < 32) {
        s_mu[t] = sum + ge0 * W1[(size_t)65536 * 32 + t] + ge1 * W1[(size_t)65537 * 32 + t] + b1[t];
    } else {
        int c = t - 32;
        float ls = sum + ge0 * W2[(size_t)65536 * 32 + c] + ge1 * W2[(size_t)65537 * 32 + c] + b2[c];
        s_sig[c] = 1e-6f + expf(ls);
    }
    __syncthreads();
    if (t < 32) s_zs0[t] = s_mu[t] + s_sig[t] * noise[b * 32 + t];
    __syncthreads();
    if (t < 32) {
        float d = linb[t];
        for (int i = 0; i < 32; i++) d = fmaf(s_zs0[i], linW[i * 32 + t], d);
        s_zs[t] = d;
        s_P[t] = softplusf(d);
    }
    __syncthreads();
    if (t < 32) {
        float mu = s_mu[t], sg = s_sig[t];
        float kld = -logf(sg) + 0.5f * (sg * sg + mu * mu - 1.f);
        float pt = s_P[t] * ws[WS_T + b * 32 + t];
        const float* Grow = ws + WS_G + g * 1024 + t * 32;
        float gd = 0.f;
        for (int j = 0; j < 32; j++) gd = fmaf(Grow[j], s_P[j], gd);
        s_red[t] = kld; s_red[32 + t] = pt; s_red[64 + t] = s_P[t] * gd;
    }
    __syncthreads();
    if (t == 0) {
        float kld = 0.f, pt = 0.f, pgp = 0.f;
        for (int i = 0; i < 32; i++) { kld += s_red[i]; pt += s_red[32 + i]; pgp += s_red[64 + i]; }
        float rec = (ws[WS_SS + b] - 2.f * pt + pgp) * (1.f / 65536.f);
        float l0 = s_zs[0] + lbias[0], l1 = s_zs[1] + lbias[1];
        float l2 = s_zs[2] + lbias[2], l3 = 1.f + lbias[3];
        float m = fmaxf(fmaxf(l0, l1), fmaxf(l2, l3));
        float lse = m + logf(expf(l0 - m) + expf(l1 - m) + expf(l2 - m) + expf(l3 - m));
        int lb = labels[b];
        float ll = ((lb == 0) ? l0 : (lb == 1) ? l1 : (lb == 2) ? l2 : l3) - lse;
        ws[WS_LOSSB + b] = rec - weights[b] * ll + kld;
    }
}

// ---- K4: final scalar ----
__global__ __launch_bounds__(256) void k4_final(const float* __restrict__ ws, float* __restrict__ out) {
    __shared__ float red[256];
    int t = threadIdx.x;
    float s = 0.f;
    for (int i = t; i < 1024; i += 256) s += ws[WS_LOSSB + i];
    red[t] = s;
    __syncthreads();
    for (int o = 128; o > 0; o >>= 1) {
        if (t < o) red[t] += red[t + o];
        __syncthreads();
    }
    if (t == 0) out[0] = red[0] * (1.f / 1024.f) + ws[WS_SCAL] + ws[WS_SCAL + 1];
}

extern "C" void kernel_launch(void* const* d_in, const int* in_sizes, int n_in,
                              void* d_out, int out_size, void* d_ws, size_t ws_size,
                              hipStream_t stream) {
    const float* feat    = (const float*)d_in[0];
    const int*   labels  = (const int*)d_in[1];
    const int*   groups  = (const int*)d_in[2];
    const float* weights = (const float*)d_in[3];
    const float* noise   = (const float*)d_in[4];
    const float* gemb    = (const float*)d_in[5];
    const float* W1      = (const float*)d_in[6];
    const float* b1      = (const float*)d_in[7];
    const float* W2      = (const float*)d_in[8];
    const float* b2      = (const float*)d_in[9];
    const float* ff      = (const float*)d_in[10];
    const float* r1f     = (const float*)d_in[11];
    const float* r2f     = (const float*)d_in[12];
    const float* linW    = (const float*)d_in[13];
    const float* linb    = (const float*)d_in[14];
    const float* lbias   = (const float*)d_in[15];
    float* ws = (float*)d_ws;
    float* out = (float*)d_out;

    // zero Z/T/SS/SCAL accumulators
    hipMemsetAsync(ws, 0, 99392 * sizeof(float), stream);

    // factors(+transposed) | W prepack | sort — independent block ranges, one launch
    k0a<<<2305, 256, 0, stream>>>(ff, r1f, r2f, W1, W2, groups, ws);
    // variance losses | Gram — one launch
    k0b<<<28, 256, 0, stream>>>(ws);
    k_fused<<<dim3(NTILE, KS1), 256, 0, stream>>>(feat, ws);
    k3_batch<<<1024, 64, 0, stream>>>(W1, W2, b1, b2, gemb, noise, linW, linb, lbias,
                                      groups, labels, weights, ws);
    k4_final<<<1, 256, 0, stream>>>(ws, out);
}

// Round 3
// 464.522 us; speedup vs baseline: 1.1853x; 1.1853x over previous
//
#include <hip/hip_runtime.h>
#include <math.h>

#define NFEAT 65536
#define KS1   32        // k slices (2048 each)
#define NTILE 32        // max 64-row group-uniform tiles

// ---- ws layout (float offsets) — identical to the harness-proven round-1 layout ----
#define WS_Z     0          // [1024][64] atomic accum mu|ls   (memset)
#define WS_T     65536      // [1024][32] atomic accum T       (memset)
#define WS_SS    98304      // [1024] sum(flat^2)              (memset)
#define WS_SCAL  99328      // [2] freq_loss, roi_loss         (memset; pad to 99392)
#define WS_FSP   99392      // [16][32][64] softplus freq
#define WS_R1SP  132160     // [16][32][32]
#define WS_R2SP  148544     // [16][32][32]
#define WS_G     164928     // [16][32][32] Gram
#define WS_LOSSB 181312     // [1024]
#define WS_SORTI 182336     // int region: order[2048], tg[32], tb[32], tc[32]
#define WS_FT    184832     // [16][64][32] softplus freq, transposed (f major)
#define WS_R1T   217600     // [16][32][32] softplus r1, transposed (r major)
#define WS_WP    233984     // bf16[8192 kg][64 col][8] fragment-packed W1|W2 (8 MB)
// end: 233984 + 2097152 = 2331136 floats = 9.33 MB (same as round 1, which passed)

typedef __bf16 bf16x8 __attribute__((ext_vector_type(8)));
typedef float  floatx4 __attribute__((ext_vector_type(4)));

__device__ __forceinline__ float softplusf(float x) {
    return fmaxf(x, 0.f) + log1pf(expf(-fabsf(x)));
}

__device__ __forceinline__ void glds16(const void* g, void* l) {
    __builtin_amdgcn_global_load_lds(
        (const __attribute__((address_space(1))) unsigned int*)g,
        (__attribute__((address_space(3))) unsigned int*)l, 16, 0, 0);
}

// ---- K0a combined: softplus factors (+transposed copies) | W prepack | sort ----
__global__ __launch_bounds__(256) void k0a(const float* __restrict__ ff,
                                           const float* __restrict__ r1,
                                           const float* __restrict__ r2,
                                           const float* __restrict__ W1,
                                           const float* __restrict__ W2,
                                           const int* __restrict__ groups,
                                           float* __restrict__ ws) {
    const int bid = blockIdx.x, t = threadIdx.x;
    __shared__ int cnt[16], pos[16];
    if (bid < 256) {
        int i = bid * 256 + t;
        if (i < 32768) {
            float sp = softplusf(ff[i]);
            ws[WS_FSP + i] = sp;
            int g = i >> 11, z = (i >> 6) & 31, f = i & 63;
            ws[WS_FT + g * 2048 + f * 32 + z] = sp;
        } else if (i < 49152) {
            int ii = i - 32768;
            float sp = softplusf(r1[ii]);
            ws[WS_R1SP + ii] = sp;
            int g = ii >> 10, z = (ii >> 5) & 31, r = ii & 31;
            ws[WS_R1T + g * 1024 + r * 32 + z] = sp;
        } else {
            int ii = i - 49152;
            ws[WS_R2SP + ii] = softplusf(r2[ii]);
        }
    } else if (bid < 2304) {
        // W prepack: fragment (kg, col) = bf16 W[(kg*8+j)][col], col 0..31->W1, 32..63->W2
        int e = (bid - 256) * 256 + t;          // 0 .. 524287
        int kg = e >> 6, col = e & 63;
        const float* Wsrc = (col < 32 ? W1 : W2) + (size_t)kg * 256 + (col & 31);
        bf16x8 o;
        #pragma unroll
        for (int j = 0; j < 8; j++) o[j] = (__bf16)Wsrc[j * 32];
        *(bf16x8*)((__bf16*)(ws + WS_WP) + (size_t)e * 8) = o;
    } else {
        // ---- sort batches by group into 64-row tiles ----
        int* order = (int*)(ws + WS_SORTI);
        int* tg = order + 2048; int* tb = order + 2080; int* tc = order + 2112;
        if (t < 16) cnt[t] = 0;
        __syncthreads();
        for (int i = t; i < 1024; i += 256) atomicAdd(&cnt[groups[i]], 1);
        __syncthreads();
        if (t == 0) {
            int tt = 0, base = 0;
            for (int g = 0; g < 16; g++) {
                pos[g] = base;
                int c = cnt[g];
                int nt = (c + 63) >> 6;
                for (int j = 0; j < nt; j++) {
                    tg[tt] = g; tb[tt] = base + j * 64;
                    int rem = c - j * 64;
                    tc[tt] = rem < 64 ? rem : 64;
                    tt++;
                }
                base += c;
            }
            for (; tt < NTILE; tt++) { tg[tt] = 0; tb[tt] = 0; tc[tt] = 0; }
        }
        __syncthreads();
        for (int i = t; i < 1024; i += 256) {
            int s = atomicAdd(&pos[groups[i]], 1);
            order[s] = i;
        }
        for (int i = 1024 + t; i < 2048; i += 256) order[i] = 0;
    }
}

// ---- K0b combined: variance losses | per-group Gram ----
__global__ __launch_bounds__(256) void k0b(float* __restrict__ ws) {
    __shared__ float red[256];
    __shared__ float Fg[2048], R1g[1024], R2g[1024];
    const int bid = blockIdx.x, t = threadIdx.x;
    if (bid < 12) {
        int gid = bid * 256 + t;
        float contrib = 0.f;
        if (gid < 2048) {
            const float* F = ws + WS_FSP + gid;
            float sx = 0.f, sx2 = 0.f;
            #pragma unroll
            for (int g = 0; g < 16; g++) { float x = F[g * 2048]; sx += x; sx2 += x * x; }
            contrib = (sx2 - sx * sx * (1.f / 16.f)) * (1.f / 15.f) * (1.f / 64.f);
        } else {
            int p = gid - 2048;
            const float* A = ws + WS_R1SP + p;
            const float* B = ws + WS_R2SP + p;
            float sx = 0.f, sx2 = 0.f, tx = 0.f, tx2 = 0.f;
            #pragma unroll
            for (int g = 0; g < 16; g++) {
                float x = A[g * 1024]; sx += x; sx2 += x * x;
                float y = B[g * 1024]; tx += y; tx2 += y * y;
            }
            contrib = ((sx2 - sx * sx * (1.f / 16.f)) + (tx2 - tx * tx * (1.f / 16.f)))
                      * (1.f / 15.f) * (1.f / 32.f);
        }
        red[t] = contrib;
        __syncthreads();
        for (int o = 128; o > 0; o >>= 1) {
            if (t < o) red[t] += red[t + o];
            __syncthreads();
        }
        if (t == 0) atomicAdd(ws + WS_SCAL + (bid < 8 ? 0 : 1), red[0]);
    } else {
        int g = bid - 12;
        for (int i = t; i < 2048; i += 256) Fg[i] = ws[WS_FSP + g * 2048 + i];
        for (int i = t; i < 1024; i += 256) {
            R1g[i] = ws[WS_R1SP + g * 1024 + i];
            R2g[i] = ws[WS_R2SP + g * 1024 + i];
        }
        __syncthreads();
        for (int p = t; p < 1024; p += 256) {
            int z1 = p >> 5, z2 = p & 31;
            float dF = 0.f;
            for (int f = 0; f < 64; f++) dF += Fg[z1 * 64 + f] * Fg[z2 * 64 + f];
            float d1 = 0.f, d2 = 0.f;
            for (int r = 0; r < 32; r++) {
                d1 += R1g[z1 * 32 + r] * R1g[z2 * 32 + r];
                d2 += R2g[z1 * 32 + r] * R2g[z2 * 32 + r];
            }
            ws[WS_G + g * 1024 + p] = dF * d1 * d2;
        }
    }
}

// ---- fused: GEMM [64 x 2048] x [2048 x 96] per block; N = W1(32)|W2(32)|Kg(32)
//      Round-0 proven structure: K-chunk=128 (16 iters), register-double-buffered A.
//      Only change: W staged via prepacked-bf16 + async global_load_lds (round-1 proven).
__global__ __launch_bounds__(256) void k_fused(const float* __restrict__ feat,
                                               float* __restrict__ wsf) {
    const int rt = blockIdx.x, ks = blockIdx.y;
    const int* order = (const int*)(wsf + WS_SORTI);
    const int tcnt = order[2112 + rt];
    if (tcnt == 0) return;
    const int g     = order[2048 + rt];
    const int tbase = order[2080 + rt];

    __shared__ __bf16 Bsm[2][12800];   // 16 kg x stride 100 cols x 8, x2 buffers
    const int tid = threadIdx.x;
    const int w = tid >> 6, lane = tid & 63;
    const int fn = lane & 15, q4 = lane >> 4;
    const size_t kbase = (size_t)ks * 2048;

    const int rowit = w * 16 + fn;
    const int bA = order[tbase + rowit];
    const float* fp = feat + (size_t)bA * NFEAT + kbase + q4 * 8;

    // Kg-gen roles
    const int kz = tid & 31, kg8 = tid >> 5;     // kg8 0..7
    const int h = kg8 >> 1;
    float r2v[16];
    {
        const float* R2g = wsf + WS_R2SP + g * 1024 + kz * 32 + (kg8 & 1) * 16;
        float4 a0 = *(const float4*)(R2g);
        float4 a1 = *(const float4*)(R2g + 4);
        float4 a2 = *(const float4*)(R2g + 8);
        float4 a3 = *(const float4*)(R2g + 12);
        r2v[0]=a0.x; r2v[1]=a0.y; r2v[2]=a0.z; r2v[3]=a0.w;
        r2v[4]=a1.x; r2v[5]=a1.y; r2v[6]=a1.z; r2v[7]=a1.w;
        r2v[8]=a2.x; r2v[9]=a2.y; r2v[10]=a2.z; r2v[11]=a2.w;
        r2v[12]=a3.x; r2v[13]=a3.y; r2v[14]=a3.z; r2v[15]=a3.w;
    }
    const float* Ftp  = wsf + WS_FT  + g * 2048 + (ks * 2) * 32 + kz;  // [(cc>>3)*32]
    const float* R1tp = wsf + WS_R1T + g * 1024 + kz;                  // [((cc&7)*4+h)*32]

    const __bf16* wp = (const __bf16*)(wsf + WS_WP);
    const size_t kgb = (size_t)ks * 256;    // kg-block base; + cc*16 + (w*4+p)

    float4 rA[2][8];

    // ---- prologue: stage chunk 0 ----
    #pragma unroll
    for (int kq = 0; kq < 4; kq++) {
        rA[0][kq * 2]     = *(const float4*)(fp + kq * 32);
        rA[0][kq * 2 + 1] = *(const float4*)(fp + kq * 32 + 4);
    }
    #pragma unroll
    for (int p = 0; p < 4; p++)
        glds16(wp + ((kgb + (size_t)(w * 4 + p)) * 64 + (size_t)lane) * 8,
               &Bsm[0][(w * 4 + p) * 800]);
    {
        float cf = Ftp[0] * R1tp[h * 32];
        #pragma unroll
        for (int ih = 0; ih < 2; ih++) {
            bf16x8 pk;
            #pragma unroll
            for (int j = 0; j < 8; j++) pk[j] = (__bf16)(cf * r2v[ih * 8 + j]);
            *(bf16x8*)&Bsm[0][((kg8 * 2 + ih) * 100 + 64 + kz) * 8] = pk;
        }
    }
    __syncthreads();

    floatx4 acc0 = {0,0,0,0}, acc1 = {0,0,0,0}, acc2 = {0,0,0,0};
    floatx4 acc3 = {0,0,0,0}, acc4 = {0,0,0,0}, acc5 = {0,0,0,0};
    float ssl = 0.f;

    #pragma unroll 2
    for (int cc = 0; cc < 16; cc++) {
        const int cur = cc & 1, nxt = cur ^ 1;
        float FvN = 0.f, R1vN = 0.f;
        if (cc < 15) {
            const float* fpn = fp + (cc + 1) * 128;
            #pragma unroll
            for (int kq = 0; kq < 4; kq++) {
                rA[nxt][kq * 2]     = *(const float4*)(fpn + kq * 32);
                rA[nxt][kq * 2 + 1] = *(const float4*)(fpn + kq * 32 + 4);
            }
            #pragma unroll
            for (int p = 0; p < 4; p++)
                glds16(wp + ((kgb + (size_t)((cc + 1) * 16 + w * 4 + p)) * 64 + (size_t)lane) * 8,
                       &Bsm[nxt][(w * 4 + p) * 800]);
            FvN  = Ftp[((cc + 1) >> 3) * 32];
            R1vN = R1tp[(((cc + 1) & 7) * 4 + h) * 32];
        }
        // compute chunk cc
        #pragma unroll
        for (int kq = 0; kq < 4; kq++) {
            float4 lo = rA[cur][kq * 2], hi = rA[cur][kq * 2 + 1];
            ssl += lo.x*lo.x + lo.y*lo.y + lo.z*lo.z + lo.w*lo.w
                 + hi.x*hi.x + hi.y*hi.y + hi.z*hi.z + hi.w*hi.w;
            bf16x8 af;
            af[0]=(__bf16)lo.x; af[1]=(__bf16)lo.y; af[2]=(__bf16)lo.z; af[3]=(__bf16)lo.w;
            af[4]=(__bf16)hi.x; af[5]=(__bf16)hi.y; af[6]=(__bf16)hi.z; af[7]=(__bf16)hi.w;
            const __bf16* bb = &Bsm[cur][((kq * 4 + q4) * 100 + fn) * 8];
            bf16x8 b0 = *(const bf16x8*)(bb);
            bf16x8 b1 = *(const bf16x8*)(bb + 16 * 8);
            bf16x8 b2 = *(const bf16x8*)(bb + 32 * 8);
            bf16x8 b3 = *(const bf16x8*)(bb + 48 * 8);
            bf16x8 b4 = *(const bf16x8*)(bb + 64 * 8);
            bf16x8 b5 = *(const bf16x8*)(bb + 80 * 8);
            acc0 = __builtin_amdgcn_mfma_f32_16x16x32_bf16(af, b0, acc0, 0, 0, 0);
            acc1 = __builtin_amdgcn_mfma_f32_16x16x32_bf16(af, b1, acc1, 0, 0, 0);
            acc2 = __builtin_amdgcn_mfma_f32_16x16x32_bf16(af, b2, acc2, 0, 0, 0);
            acc3 = __builtin_amdgcn_mfma_f32_16x16x32_bf16(af, b3, acc3, 0, 0, 0);
            acc4 = __builtin_amdgcn_mfma_f32_16x16x32_bf16(af, b4, acc4, 0, 0, 0);
            acc5 = __builtin_amdgcn_mfma_f32_16x16x32_bf16(af, b5, acc5, 0, 0, 0);
        }
        if (cc < 15) {
            float cf = FvN * R1vN;
            #pragma unroll
            for (int ih = 0; ih < 2; ih++) {
                bf16x8 pk;
                #pragma unroll
                for (int j = 0; j < 8; j++) pk[j] = (__bf16)(cf * r2v[ih * 8 + j]);
                *(bf16x8*)&Bsm[nxt][((kg8 * 2 + ih) * 100 + 64 + kz) * 8] = pk;
            }
        }
        __syncthreads();
    }

    // ---- epilogue (round-0 proven atomics) ----
    float ssv = ssl + __shfl_xor(ssl, 16, 64);
    ssv += __shfl_xor(ssv, 32, 64);
    if (q4 == 0 && rowit < tcnt) atomicAdd(wsf + WS_SS + bA, ssv);

    #pragma unroll
    for (int r = 0; r < 4; r++) {
        int rit = w * 16 + q4 * 4 + r;
        if (rit < tcnt) {
            int b = order[tbase + rit];
            atomicAdd(wsf + WS_Z + b * 64 +  0 + fn, acc0[r]);
            atomicAdd(wsf + WS_Z + b * 64 + 16 + fn, acc1[r]);
            atomicAdd(wsf + WS_Z + b * 64 + 32 + fn, acc2[r]);
            atomicAdd(wsf + WS_Z + b * 64 + 48 + fn, acc3[r]);
            atomicAdd(wsf + WS_T + b * 32 +  0 + fn, acc4[r]);
            atomicAdd(wsf + WS_T + b * 32 + 16 + fn, acc5[r]);
        }
    }
}

// ---- K3: per-batch epilogue ----
__global__ __launch_bounds__(64) void k3_batch(const float* __restrict__ W1,
                                               const float* __restrict__ W2,
                                               const float* __restrict__ b1,
                                               const float* __restrict__ b2,
                                               const float* __restrict__ gemb,
                                               const float* __restrict__ noise,
                                               const float* __restrict__ linW,
                                               const float* __restrict__ linb,
                                               const float* __restrict__ lbias,
                                               const int* __restrict__ groups,
                                               const int* __restrict__ labels,
                                               const float* __restrict__ weights,
                                               float* __restrict__ ws) {
    const int b = blockIdx.x;
    const int t = threadIdx.x;
    const int g = groups[b];
    float sum = ws[WS_Z + b * 64 + t];

    __shared__ float s_mu[32], s_sig[32], s_zs0[32], s_zs[32], s_P[32], s_red[96];
    float ge0 = gemb[g * 2], ge1 = gemb[g * 2 + 1];
    if (t < 32) {
        s_mu[t] = sum + ge0 * W1[(size_t)65536 * 32 + t] + ge1 * W1[(size_t)65537 * 32 + t] + b1[t];
    } else {
        int c = t - 32;
        float ls = sum + ge0 * W2[(size_t)65536 * 32 + c] + ge1 * W2[(size_t)65537 * 32 + c] + b2[c];
        s_sig[c] = 1e-6f + expf(ls);
    }
    __syncthreads();
    if (t < 32) s_zs0[t] = s_mu[t] + s_sig[t] * noise[b * 32 + t];
    __syncthreads();
    if (t < 32) {
        float d = linb[t];
        for (int i = 0; i < 32; i++) d = fmaf(s_zs0[i], linW[i * 32 + t], d);
        s_zs[t] = d;
        s_P[t] = softplusf(d);
    }
    __syncthreads();
    if (t < 32) {
        float mu = s_mu[t], sg = s_sig[t];
        float kld = -logf(sg) + 0.5f * (sg * sg + mu * mu - 1.f);
        float pt = s_P[t] * ws[WS_T + b * 32 + t];
        const float* Grow = ws + WS_G + g * 1024 + t * 32;
        float gd = 0.f;
        for (int j = 0; j < 32; j++) gd = fmaf(Grow[j], s_P[j], gd);
        s_red[t] = kld; s_red[32 + t] = pt; s_red[64 + t] = s_P[t] * gd;
    }
    __syncthreads();
    if (t == 0) {
        float kld = 0.f, pt = 0.f, pgp = 0.f;
        for (int i = 0; i < 32; i++) { kld += s_red[i]; pt += s_red[32 + i]; pgp += s_red[64 + i]; }
        float rec = (ws[WS_SS + b] - 2.f * pt + pgp) * (1.f / 65536.f);
        float l0 = s_zs[0] + lbias[0], l1 = s_zs[1] + lbias[1];
        float l2 = s_zs[2] + lbias[2], l3 = 1.f + lbias[3];
        float m = fmaxf(fmaxf(l0, l1), fmaxf(l2, l3));
        float lse = m + logf(expf(l0 - m) + expf(l1 - m) + expf(l2 - m) + expf(l3 - m));
        int lb = labels[b];
        float ll = ((lb == 0) ? l0 : (lb == 1) ? l1 : (lb == 2) ? l2 : l3) - lse;
        ws[WS_LOSSB + b] = rec - weights[b] * ll + kld;
    }
}

// ---- K4: final scalar ----
__global__ __launch_bounds__(256) void k4_final(const float* __restrict__ ws, float* __restrict__ out) {
    __shared__ float red[256];
    int t = threadIdx.x;
    float s = 0.f;
    for (int i = t; i < 1024; i += 256) s += ws[WS_LOSSB + i];
    red[t] = s;
    __syncthreads();
    for (int o = 128; o > 0; o >>= 1) {
        if (t < o) red[t] += red[t + o];
        __syncthreads();
    }
    if (t == 0) out[0] = red[0] * (1.f / 1024.f) + ws[WS_SCAL] + ws[WS_SCAL + 1];
}

extern "C" void kernel_launch(void* const* d_in, const int* in_sizes, int n_in,
                              void* d_out, int out_size, void* d_ws, size_t ws_size,
                              hipStream_t stream) {
    const float* feat    = (const float*)d_in[0];
    const int*   labels  = (const int*)d_in[1];
    const int*   groups  = (const int*)d_in[2];
    const float* weights = (const float*)d_in[3];
    const float* noise   = (const float*)d_in[4];
    const float* gemb    = (const float*)d_in[5];
    const float* W1      = (const float*)d_in[6];
    const float* b1      = (const float*)d_in[7];
    const float* W2      = (const float*)d_in[8];
    const float* b2      = (const float*)d_in[9];
    const float* ff      = (const float*)d_in[10];
    const float* r1f     = (const float*)d_in[11];
    const float* r2f     = (const float*)d_in[12];
    const float* linW    = (const float*)d_in[13];
    const float* linb    = (const float*)d_in[14];
    const float* lbias   = (const float*)d_in[15];
    float* ws = (float*)d_ws;
    float* out = (float*)d_out;

    // zero Z/T/SS/SCAL accumulators
    hipMemsetAsync(ws, 0, 99392 * sizeof(float), stream);

    // factors(+transposed) | W prepack | sort — one launch
    k0a<<<2305, 256, 0, stream>>>(ff, r1f, r2f, W1, W2, groups, ws);
    // variance losses | Gram — one launch
    k0b<<<28, 256, 0, stream>>>(ws);
    k_fused<<<dim3(NTILE, KS1), 256, 0, stream>>>(feat, ws);
    k3_batch<<<1024, 64, 0, stream>>>(W1, W2, b1, b2, gemb, noise, linW, linb, lbias,
                                      groups, labels, weights, ws);
    k4_final<<<1, 256, 0, stream>>>(ws, out);
}

// Round 4
// 460.456 us; speedup vs baseline: 1.1958x; 1.0088x over previous
//
#include <hip/hip_runtime.h>
#include <math.h>

#define NFEAT 65536
#define KS1   32        // k slices (2048 each)
#define NTILE 32        // max 64-row group-uniform tiles

// ---- ws layout (float offsets) — identical to the harness-proven round-1/3 layout ----
#define WS_Z     0          // [1024][64] atomic accum mu|ls   (memset)
#define WS_T     65536      // [1024][32] atomic accum T       (memset)
#define WS_SS    98304      // [1024] sum(flat^2)              (memset)
#define WS_SCAL  99328      // [2] freq_loss, roi_loss         (memset; pad to 99392)
#define WS_FSP   99392      // [16][32][64] softplus freq
#define WS_R1SP  132160     // [16][32][32]
#define WS_R2SP  148544     // [16][32][32]
#define WS_G     164928     // [16][32][32] Gram
#define WS_LOSSB 181312     // [1024]
#define WS_SORTI 182336     // int region: order[2048], tg[32], tb[32], tc[32]
#define WS_FT    184832     // [16][64][32] softplus freq, transposed (f major)
#define WS_R1T   217600     // [16][32][32] softplus r1, transposed (r major)
#define WS_WP    233984     // bf16[8192 kg][64 col][8] fragment-packed W1|W2 (8 MB)
// end: 233984 + 2097152 = 2331136 floats = 9.33 MB

typedef __bf16 bf16x8 __attribute__((ext_vector_type(8)));
typedef float  floatx4 __attribute__((ext_vector_type(4)));

__device__ __forceinline__ float softplusf(float x) {
    return fmaxf(x, 0.f) + log1pf(expf(-fabsf(x)));
}

__device__ __forceinline__ void glds16(const void* g, void* l) {
    __builtin_amdgcn_global_load_lds(
        (const __attribute__((address_space(1))) unsigned int*)g,
        (__attribute__((address_space(3))) unsigned int*)l, 16, 0, 0);
}

// ---- K0a combined: softplus factors (+transposed copies) | W prepack | sort ----
__global__ __launch_bounds__(256) void k0a(const float* __restrict__ ff,
                                           const float* __restrict__ r1,
                                           const float* __restrict__ r2,
                                           const float* __restrict__ W1,
                                           const float* __restrict__ W2,
                                           const int* __restrict__ groups,
                                           float* __restrict__ ws) {
    const int bid = blockIdx.x, t = threadIdx.x;
    __shared__ int cnt[16], pos[16];
    if (bid < 256) {
        int i = bid * 256 + t;
        if (i < 32768) {
            float sp = softplusf(ff[i]);
            ws[WS_FSP + i] = sp;
            int g = i >> 11, z = (i >> 6) & 31, f = i & 63;
            ws[WS_FT + g * 2048 + f * 32 + z] = sp;
        } else if (i < 49152) {
            int ii = i - 32768;
            float sp = softplusf(r1[ii]);
            ws[WS_R1SP + ii] = sp;
            int g = ii >> 10, z = (ii >> 5) & 31, r = ii & 31;
            ws[WS_R1T + g * 1024 + r * 32 + z] = sp;
        } else {
            int ii = i - 49152;
            ws[WS_R2SP + ii] = softplusf(r2[ii]);
        }
    } else if (bid < 2304) {
        // W prepack: fragment (kg, col) = bf16 W[(kg*8+j)][col], col 0..31->W1, 32..63->W2
        int e = (bid - 256) * 256 + t;          // 0 .. 524287
        int kg = e >> 6, col = e & 63;
        const float* Wsrc = (col < 32 ? W1 : W2) + (size_t)kg * 256 + (col & 31);
        bf16x8 o;
        #pragma unroll
        for (int j = 0; j < 8; j++) o[j] = (__bf16)Wsrc[j * 32];
        *(bf16x8*)((__bf16*)(ws + WS_WP) + (size_t)e * 8) = o;
    } else {
        // ---- sort batches by group into 64-row tiles ----
        int* order = (int*)(ws + WS_SORTI);
        int* tg = order + 2048; int* tb = order + 2080; int* tc = order + 2112;
        if (t < 16) cnt[t] = 0;
        __syncthreads();
        for (int i = t; i < 1024; i += 256) atomicAdd(&cnt[groups[i]], 1);
        __syncthreads();
        if (t == 0) {
            int tt = 0, base = 0;
            for (int g = 0; g < 16; g++) {
                pos[g] = base;
                int c = cnt[g];
                int nt = (c + 63) >> 6;
                for (int j = 0; j < nt; j++) {
                    tg[tt] = g; tb[tt] = base + j * 64;
                    int rem = c - j * 64;
                    tc[tt] = rem < 64 ? rem : 64;
                    tt++;
                }
                base += c;
            }
            for (; tt < NTILE; tt++) { tg[tt] = 0; tb[tt] = 0; tc[tt] = 0; }
        }
        __syncthreads();
        for (int i = t; i < 1024; i += 256) {
            int s = atomicAdd(&pos[groups[i]], 1);
            order[s] = i;
        }
        for (int i = 1024 + t; i < 2048; i += 256) order[i] = 0;
    }
}

// ---- K0b combined: variance losses | per-group Gram ----
__global__ __launch_bounds__(256) void k0b(float* __restrict__ ws) {
    __shared__ float red[256];
    __shared__ float Fg[2048], R1g[1024], R2g[1024];
    const int bid = blockIdx.x, t = threadIdx.x;
    if (bid < 12) {
        int gid = bid * 256 + t;
        float contrib = 0.f;
        if (gid < 2048) {
            const float* F = ws + WS_FSP + gid;
            float sx = 0.f, sx2 = 0.f;
            #pragma unroll
            for (int g = 0; g < 16; g++) { float x = F[g * 2048]; sx += x; sx2 += x * x; }
            contrib = (sx2 - sx * sx * (1.f / 16.f)) * (1.f / 15.f) * (1.f / 64.f);
        } else {
            int p = gid - 2048;
            const float* A = ws + WS_R1SP + p;
            const float* B = ws + WS_R2SP + p;
            float sx = 0.f, sx2 = 0.f, tx = 0.f, tx2 = 0.f;
            #pragma unroll
            for (int g = 0; g < 16; g++) {
                float x = A[g * 1024]; sx += x; sx2 += x * x;
                float y = B[g * 1024]; tx += y; tx2 += y * y;
            }
            contrib = ((sx2 - sx * sx * (1.f / 16.f)) + (tx2 - tx * tx * (1.f / 16.f)))
                      * (1.f / 15.f) * (1.f / 32.f);
        }
        red[t] = contrib;
        __syncthreads();
        for (int o = 128; o > 0; o >>= 1) {
            if (t < o) red[t] += red[t + o];
            __syncthreads();
        }
        if (t == 0) atomicAdd(ws + WS_SCAL + (bid < 8 ? 0 : 1), red[0]);
    } else {
        int g = bid - 12;
        for (int i = t; i < 2048; i += 256) Fg[i] = ws[WS_FSP + g * 2048 + i];
        for (int i = t; i < 1024; i += 256) {
            R1g[i] = ws[WS_R1SP + g * 1024 + i];
            R2g[i] = ws[WS_R2SP + g * 1024 + i];
        }
        __syncthreads();
        for (int p = t; p < 1024; p += 256) {
            int z1 = p >> 5, z2 = p & 31;
            float dF = 0.f;
            for (int f = 0; f < 64; f++) dF += Fg[z1 * 64 + f] * Fg[z2 * 64 + f];
            float d1 = 0.f, d2 = 0.f;
            for (int r = 0; r < 32; r++) {
                d1 += R1g[z1 * 32 + r] * R1g[z2 * 32 + r];
                d2 += R2g[z1 * 32 + r] * R2g[z2 * 32 + r];
            }
            ws[WS_G + g * 1024 + p] = dF * d1 * d2;
        }
    }
}

// ---- fused: GEMM [64 x 2048] x [2048 x 96] per block; N = W1(32)|W2(32)|Kg(32)
//      K-chunk = 128 (16 iters), register-double-buffered A, glds16 W staging.
//      NEW: counted-vmcnt barrier (T4) — A-prefetch stays in flight across s_barrier.
__global__ __launch_bounds__(256) void k_fused(const float* __restrict__ feat,
                                               float* __restrict__ wsf) {
    const int rt = blockIdx.x, ks = blockIdx.y;
    const int* order = (const int*)(wsf + WS_SORTI);
    const int tcnt = order[2112 + rt];
    if (tcnt == 0) return;
    const int g     = order[2048 + rt];
    const int tbase = order[2080 + rt];

    __shared__ __bf16 Bsm[2][12800];   // 16 kg x stride 100 cols x 8, x2 buffers
    const int tid = threadIdx.x;
    const int w = tid >> 6, lane = tid & 63;
    const int fn = lane & 15, q4 = lane >> 4;
    const size_t kbase = (size_t)ks * 2048;

    const int rowit = w * 16 + fn;
    const int bA = order[tbase + rowit];
    const float* fp = feat + (size_t)bA * NFEAT + kbase + q4 * 8;

    // Kg-gen roles
    const int kz = tid & 31, kg8 = tid >> 5;     // kg8 0..7
    const int h = kg8 >> 1;
    float r2v[16];
    {
        const float* R2g = wsf + WS_R2SP + g * 1024 + kz * 32 + (kg8 & 1) * 16;
        float4 a0 = *(const float4*)(R2g);
        float4 a1 = *(const float4*)(R2g + 4);
        float4 a2 = *(const float4*)(R2g + 8);
        float4 a3 = *(const float4*)(R2g + 12);
        r2v[0]=a0.x; r2v[1]=a0.y; r2v[2]=a0.z; r2v[3]=a0.w;
        r2v[4]=a1.x; r2v[5]=a1.y; r2v[6]=a1.z; r2v[7]=a1.w;
        r2v[8]=a2.x; r2v[9]=a2.y; r2v[10]=a2.z; r2v[11]=a2.w;
        r2v[12]=a3.x; r2v[13]=a3.y; r2v[14]=a3.z; r2v[15]=a3.w;
    }
    const float* Ftp  = wsf + WS_FT  + g * 2048 + (ks * 2) * 32 + kz;  // [(chunk>>3)*32]
    const float* R1tp = wsf + WS_R1T + g * 1024 + kz;                  // [((chunk&7)*4+h)*32]

    const __bf16* wp = (const __bf16*)(wsf + WS_WP);
    const size_t kgb = (size_t)ks * 256;    // kg-block base; + cc*16 + (w*4+p)

    float4 rA[2][8];

    // ---- prologue: stage chunk 0; preload chunk-1 factor scalars ----
    #pragma unroll
    for (int p = 0; p < 4; p++)
        glds16(wp + ((kgb + (size_t)(w * 4 + p)) * 64 + (size_t)lane) * 8,
               &Bsm[0][(w * 4 + p) * 800]);
    #pragma unroll
    for (int kq = 0; kq < 4; kq++) {
        rA[0][kq * 2]     = *(const float4*)(fp + kq * 32);
        rA[0][kq * 2 + 1] = *(const float4*)(fp + kq * 32 + 4);
    }
    float fvF = Ftp[(1 >> 3) * 32];            // chunk-1 factors (staged during cc=0)
    float fvR = R1tp[((1 & 7) * 4 + h) * 32];
    {
        float cf = Ftp[0] * R1tp[h * 32];      // chunk-0 factors
        #pragma unroll
        for (int ih = 0; ih < 2; ih++) {
            bf16x8 pk;
            #pragma unroll
            for (int j = 0; j < 8; j++) pk[j] = (__bf16)(cf * r2v[ih * 8 + j]);
            *(bf16x8*)&Bsm[0][((kg8 * 2 + ih) * 100 + 64 + kz) * 8] = pk;
        }
    }
    __syncthreads();   // prologue: full drain once (covers glds chunk 0)

    floatx4 acc0 = {0,0,0,0}, acc1 = {0,0,0,0}, acc2 = {0,0,0,0};
    floatx4 acc3 = {0,0,0,0}, acc4 = {0,0,0,0}, acc5 = {0,0,0,0};
    float ssl = 0.f;

    #pragma unroll 2
    for (int cc = 0; cc < 16; cc++) {
        const int cur = cc & 1, nxt = cur ^ 1;
        float nF = 0.f, nR = 0.f;
        if (cc < 15) {
            // VMEM issue order is pinned: [4 glds][8 A][2 f].
            #pragma unroll
            for (int p = 0; p < 4; p++)
                glds16(wp + ((kgb + (size_t)((cc + 1) * 16 + w * 4 + p)) * 64 + (size_t)lane) * 8,
                       &Bsm[nxt][(w * 4 + p) * 800]);
            __builtin_amdgcn_sched_barrier(0);
            const float* fpn = fp + (cc + 1) * 128;
            #pragma unroll
            for (int kq = 0; kq < 4; kq++) {
                rA[nxt][kq * 2]     = *(const float4*)(fpn + kq * 32);
                rA[nxt][kq * 2 + 1] = *(const float4*)(fpn + kq * 32 + 4);
            }
            __builtin_amdgcn_sched_barrier(0);
            nF = Ftp[((cc + 2) >> 3) * 32];                 // chunk cc+2 (harmless
            nR = R1tp[(((cc + 2) & 7) * 4 + h) * 32];       //  dummy read at cc=14)
            __builtin_amdgcn_sched_barrier(0);
        }
        // compute chunk cc
        __builtin_amdgcn_s_setprio(1);
        #pragma unroll
        for (int kq = 0; kq < 4; kq++) {
            float4 lo = rA[cur][kq * 2], hi = rA[cur][kq * 2 + 1];
            ssl += lo.x*lo.x + lo.y*lo.y + lo.z*lo.z + lo.w*lo.w
                 + hi.x*hi.x + hi.y*hi.y + hi.z*hi.z + hi.w*hi.w;
            bf16x8 af;
            af[0]=(__bf16)lo.x; af[1]=(__bf16)lo.y; af[2]=(__bf16)lo.z; af[3]=(__bf16)lo.w;
            af[4]=(__bf16)hi.x; af[5]=(__bf16)hi.y; af[6]=(__bf16)hi.z; af[7]=(__bf16)hi.w;
            const __bf16* bb = &Bsm[cur][((kq * 4 + q4) * 100 + fn) * 8];
            bf16x8 b0 = *(const bf16x8*)(bb);
            bf16x8 b1 = *(const bf16x8*)(bb + 16 * 8);
            bf16x8 b2 = *(const bf16x8*)(bb + 32 * 8);
            bf16x8 b3 = *(const bf16x8*)(bb + 48 * 8);
            bf16x8 b4 = *(const bf16x8*)(bb + 64 * 8);
            bf16x8 b5 = *(const bf16x8*)(bb + 80 * 8);
            acc0 = __builtin_amdgcn_mfma_f32_16x16x32_bf16(af, b0, acc0, 0, 0, 0);
            acc1 = __builtin_amdgcn_mfma_f32_16x16x32_bf16(af, b1, acc1, 0, 0, 0);
            acc2 = __builtin_amdgcn_mfma_f32_16x16x32_bf16(af, b2, acc2, 0, 0, 0);
            acc3 = __builtin_amdgcn_mfma_f32_16x16x32_bf16(af, b3, acc3, 0, 0, 0);
            acc4 = __builtin_amdgcn_mfma_f32_16x16x32_bf16(af, b4, acc4, 0, 0, 0);
            acc5 = __builtin_amdgcn_mfma_f32_16x16x32_bf16(af, b5, acc5, 0, 0, 0);
        }
        __builtin_amdgcn_s_setprio(0);
        if (cc < 15) {
            // stage Kg(chunk cc+1) with factors preloaded one iteration ago
            float cf = fvF * fvR;
            #pragma unroll
            for (int ih = 0; ih < 2; ih++) {
                bf16x8 pk;
                #pragma unroll
                for (int j = 0; j < 8; j++) pk[j] = (__bf16)(cf * r2v[ih * 8 + j]);
                *(bf16x8*)&Bsm[nxt][((kg8 * 2 + ih) * 100 + 64 + kz) * 8] = pk;
            }
            fvF = nF; fvR = nR;
            // counted barrier: drain ONLY the 4 glds (oldest); 8 A + 2 f stay in flight.
            asm volatile("s_waitcnt vmcnt(10) lgkmcnt(0)" ::: "memory");
            __builtin_amdgcn_sched_barrier(0);
            __builtin_amdgcn_s_barrier();
        }
    }

    // ---- epilogue (proven atomics) ----
    float ssv = ssl + __shfl_xor(ssl, 16, 64);
    ssv += __shfl_xor(ssv, 32, 64);
    if (q4 == 0 && rowit < tcnt) atomicAdd(wsf + WS_SS + bA, ssv);

    #pragma unroll
    for (int r = 0; r < 4; r++) {
        int rit = w * 16 + q4 * 4 + r;
        if (rit < tcnt) {
            int b = order[tbase + rit];
            atomicAdd(wsf + WS_Z + b * 64 +  0 + fn, acc0[r]);
            atomicAdd(wsf + WS_Z + b * 64 + 16 + fn, acc1[r]);
            atomicAdd(wsf + WS_Z + b * 64 + 32 + fn, acc2[r]);
            atomicAdd(wsf + WS_Z + b * 64 + 48 + fn, acc3[r]);
            atomicAdd(wsf + WS_T + b * 32 +  0 + fn, acc4[r]);
            atomicAdd(wsf + WS_T + b * 32 + 16 + fn, acc5[r]);
        }
    }
}

// ---- K3: per-batch epilogue ----
__global__ __launch_bounds__(64) void k3_batch(const float* __restrict__ W1,
                                               const float* __restrict__ W2,
                                               const float* __restrict__ b1,
                                               const float* __restrict__ b2,
                                               const float* __restrict__ gemb,
                                               const float* __restrict__ noise,
                                               const float* __restrict__ linW,
                                               const float* __restrict__ linb,
                                               const float* __restrict__ lbias,
                                               const int* __restrict__ groups,
                                               const int* __restrict__ labels,
                                               const float* __restrict__ weights,
                                               float* __restrict__ ws) {
    const int b = blockIdx.x;
    const int t = threadIdx.x;
    const int g = groups[b];
    float sum = ws[WS_Z + b * 64 + t];

    __shared__ float s_mu[32], s_sig[32], s_zs0[32], s_zs[32], s_P[32], s_red[96];
    float ge0 = gemb[g * 2], ge1 = gemb[g * 2 + 1];
    if (t < 32) {
        s_mu[t] = sum + ge0 * W1[(size_t)65536 * 32 + t] + ge1 * W1[(size_t)65537 * 32 + t] + b1[t];
    } else {
        int c = t - 32;
        float ls = sum + ge0 * W2[(size_t)65536 * 32 + c] + ge1 * W2[(size_t)65537 * 32 + c] + b2[c];
        s_sig[c] = 1e-6f + expf(ls);
    }
    __syncthreads();
    if (t < 32) s_zs0[t] = s_mu[t] + s_sig[t] * noise[b * 32 + t];
    __syncthreads();
    if (t < 32) {
        float d = linb[t];
        for (int i = 0; i < 32; i++) d = fmaf(s_zs0[i], linW[i * 32 + t], d);
        s_zs[t] = d;
        s_P[t] = softplusf(d);
    }
    __syncthreads();
    if (t < 32) {
        float mu = s_mu[t], sg = s_sig[t];
        float kld = -logf(sg) + 0.5f * (sg * sg + mu * mu - 1.f);
        float pt = s_P[t] * ws[WS_T + b * 32 + t];
        const float* Grow = ws + WS_G + g * 1024 + t * 32;
        float gd = 0.f;
        for (int j = 0; j < 32; j++) gd = fmaf(Grow[j], s_P[j], gd);
        s_red[t] = kld; s_red[32 + t] = pt; s_red[64 + t] = s_P[t] * gd;
    }
    __syncthreads();
    if (t == 0) {
        float kld = 0.f, pt = 0.f, pgp = 0.f;
        for (int i = 0; i < 32; i++) { kld += s_red[i]; pt += s_red[32 + i]; pgp += s_red[64 + i]; }
        float rec = (ws[WS_SS + b] - 2.f * pt + pgp) * (1.f / 65536.f);
        float l0 = s_zs[0] + lbias[0], l1 = s_zs[1] + lbias[1];
        float l2 = s_zs[2] + lbias[2], l3 = 1.f + lbias[3];
        float m = fmaxf(fmaxf(l0, l1), fmaxf(l2, l3));
        float lse = m + logf(expf(l0 - m) + expf(l1 - m) + expf(l2 - m) + expf(l3 - m));
        int lb = labels[b];
        float ll = ((lb == 0) ? l0 : (lb == 1) ? l1 : (lb == 2) ? l2 : l3) - lse;
        ws[WS_LOSSB + b] = rec - weights[b] * ll + kld;
    }
}

// ---- K4: final scalar ----
__global__ __launch_bounds__(256) void k4_final(const float* __restrict__ ws, float* __restrict__ out) {
    __shared__ float red[256];
    int t = threadIdx.x;
    float s = 0.f;
    for (int i = t; i < 1024; i += 256) s += ws[WS_LOSSB + i];
    red[t] = s;
    __syncthreads();
    for (int o = 128; o > 0; o >>= 1) {
        if (t < o) red[t] += red[t + o];
        __syncthreads();
    }
    if (t == 0) out[0] = red[0] * (1.f / 1024.f) + ws[WS_SCAL] + ws[WS_SCAL + 1];
}

extern "C" void kernel_launch(void* const* d_in, const int* in_sizes, int n_in,
                              void* d_out, int out_size, void* d_ws, size_t ws_size,
                              hipStream_t stream) {
    const float* feat    = (const float*)d_in[0];
    const int*   labels  = (const int*)d_in[1];
    const int*   groups  = (const int*)d_in[2];
    const float* weights = (const float*)d_in[3];
    const float* noise   = (const float*)d_in[4];
    const float* gemb    = (const float*)d_in[5];
    const float* W1      = (const float*)d_in[6];
    const float* b1      = (const float*)d_in[7];
    const float* W2      = (const float*)d_in[8];
    const float* b2      = (const float*)d_in[9];
    const float* ff      = (const float*)d_in[10];
    const float* r1f     = (const float*)d_in[11];
    const float* r2f     = (const float*)d_in[12];
    const float* linW    = (const float*)d_in[13];
    const float* linb    = (const float*)d_in[14];
    const float* lbias   = (const float*)d_in[15];
    float* ws = (float*)d_ws;
    float* out = (float*)d_out;

    // zero Z/T/SS/SCAL accumulators
    hipMemsetAsync(ws, 0, 99392 * sizeof(float), stream);

    // factors(+transposed) | W prepack | sort — one launch
    k0a<<<2305, 256, 0, stream>>>(ff, r1f, r2f, W1, W2, groups, ws);
    // variance losses | Gram — one launch
    k0b<<<28, 256, 0, stream>>>(ws);
    k_fused<<<dim3(NTILE, KS1), 256, 0, stream>>>(feat, ws);
    k3_batch<<<1024, 64, 0, stream>>>(W1, W2, b1, b2, gemb, noise, linW, linb, lbias,
                                      groups, labels, weights, ws);
    k4_final<<<1, 256, 0, stream>>>(ws, out);
}